// Round 15
// baseline (195.481 us; speedup 1.0000x reference)
//
#include <hip/hip_runtime.h>
#include <stdint.h>

typedef unsigned short u16;
typedef unsigned int u32;

#define B_    2
#define DK    64
#define T_    2048
#define S_    2048
#define CI    512
#define CO    512
#define E_    512

typedef short  short8 __attribute__((ext_vector_type(8)));
typedef __bf16 bf16x8 __attribute__((ext_vector_type(8)));
typedef float  f32x4  __attribute__((ext_vector_type(4)));

static __device__ __forceinline__ u16 f2bf(float f) {
    return __builtin_bit_cast(u16, (__bf16)f);
}

static __device__ __forceinline__ float bf2f(u16 h) {
    return __uint_as_float((u32)h << 16);
}

static __device__ __forceinline__ short8 ld8(const u16* p) {
    return *(const short8*)p;
}

static __device__ __forceinline__ f32x4 mfma_bf16(short8 a, short8 b, f32x4 c) {
    return __builtin_amdgcn_mfma_f32_16x16x32_bf16(
        __builtin_bit_cast(bf16x8, a), __builtin_bit_cast(bf16x8, b), c, 0, 0, 0);
}

// ---------------- fused prep (vectorized): x/y transpose + weight cvt + mask^T ----------------
// R14 post-mortem: prep's transposes used scalar 4B loads / 2B stores (G13: ~2x
// penalty). Now 64x64 tiles, float4 (16B) loads, short8 (16B) bf16 stores,
// LDS [64][65] pad (column reads = 2-way bank alias = free). 8704 -> 2560 blocks.
// bid < 1024: x/y transpose; < 1536: weight cvt; >= 1536: mask^T (+nonzero detect).
__global__ __launch_bounds__(256) void k_prep(const float* __restrict__ x, const float* __restrict__ y,
                                              const float* __restrict__ wk, const float* __restrict__ wv,
                                              const float* __restrict__ wq, const float* __restrict__ wf,
                                              const float* __restrict__ mask,
                                              u16* __restrict__ xt, u16* __restrict__ yt,
                                              u16* __restrict__ wkb, u16* __restrict__ wvb,
                                              u16* __restrict__ wqb, u16* __restrict__ wfb,
                                              u16* __restrict__ mt, u32* __restrict__ mflag) {
    __shared__ float tile[64][65];
    int bid = blockIdx.x;
    if (bid < 1024) {
        // transpose + cvt: src[b][i][t] f32 -> dst[b][t][i] bf16, 64x64 tile
        int bx = bid & 31, by = (bid >> 5) & 7, bz = bid >> 8;
        int tsel = bz >> 1, b = bz & 1;
        const float* src = tsel ? y : x;
        u16* dst = tsel ? yt : xt;
        int t0 = bx * 64, i0 = by * 64;
        int tx = threadIdx.x & 15, ty = threadIdx.x >> 4;   // tx: float4 idx, ty: row in group
#pragma unroll
        for (int r = 0; r < 4; r++) {
            int i = ty + r * 16;
            *(float4*)&tile[i][tx * 4] =
                *(const float4*)(src + (size_t)(b * CI + i0 + i) * T_ + t0 + tx * 4);
        }
        __syncthreads();
        int tx2 = threadIdx.x & 7, ty2 = threadIdx.x >> 3;  // tx2: 8-i chunk, ty2: t row
#pragma unroll
        for (int r = 0; r < 2; r++) {
            int t = ty2 + r * 32;
            short8 o;
#pragma unroll
            for (int j = 0; j < 8; j++)
                o[j] = (short)f2bf(tile[tx2 * 8 + j][t]);
            *(short8*)(dst + (size_t)(b * T_ + t0 + t) * CI + i0 + tx2 * 8) = o;
        }
    } else if (bid < 1536) {
        // weight cvt, 8 elems/thread (512 blocks x 256 thr x 8 = 1M elems)
        int off = ((bid - 1024) * 256 + threadIdx.x) * 8;
        int w = off >> 18, r = off & 262143;
        const float* s = (w == 0) ? wk : (w == 1) ? wv : (w == 2) ? wq : wf;
        u16* d = (w == 0) ? wkb : (w == 1) ? wvb : (w == 2) ? wqb : wfb;
        float4 a0 = *(const float4*)(s + r);
        float4 a1 = *(const float4*)(s + r + 4);
        short8 o;
        o[0] = f2bf(a0.x); o[1] = f2bf(a0.y); o[2] = f2bf(a0.z); o[3] = f2bf(a0.w);
        o[4] = f2bf(a1.x); o[5] = f2bf(a1.y); o[6] = f2bf(a1.z); o[7] = f2bf(a1.w);
        *(short8*)(d + r) = o;
    } else {
        // mask transpose + pre-scale: mask[t][s] f32 -> mt[s][t] bf16*msc; 64x64 tile
        int mb = bid - 1536;
        int bx = mb & 31, by = mb >> 5;                      // bx: t-tile, by: s-tile
        int t0 = bx * 64, s0 = by * 64;
        int tx = threadIdx.x & 15, ty = threadIdx.x >> 4;
        const float msc = 0.125f * 1.44269504088896f;
        bool nz = false;
#pragma unroll
        for (int r = 0; r < 4; r++) {
            int t = ty + r * 16;
            float4 v = *(const float4*)(mask + (size_t)(t0 + t) * S_ + s0 + tx * 4);
            nz |= (v.x != 0.0f) | (v.y != 0.0f) | (v.z != 0.0f) | (v.w != 0.0f);
            *(float4*)&tile[t][tx * 4] = v;
        }
        if (mflag && __any(nz) && (threadIdx.x & 63) == 0)
            atomicOr(mflag, 1u);
        __syncthreads();
        int tx2 = threadIdx.x & 7, ty2 = threadIdx.x >> 3;
#pragma unroll
        for (int r = 0; r < 2; r++) {
            int s = ty2 + r * 32;
            short8 o;
#pragma unroll
            for (int j = 0; j < 8; j++)
                o[j] = (short)f2bf(tile[tx2 * 8 + j][s] * msc);
            *(short8*)(mt + (size_t)(s0 + s) * T_ + t0 + tx2 * 8) = o;
        }
    }
}

// ---------------- fused projection GEMMs (R11 geometry: 64t x 128e, pipelined) ----------------
// Measured-best shape (R14): block 64t x 128e, wave 32t x 64e, grid 768 fused.
// p = p_base + (blockIdx.x>>8): 0=Q (yt->QT, pre-scaled by sc), 1=K, 2=V.
__global__ __launch_bounds__(256) void k_proj3(const u16* __restrict__ xt, const u16* __restrict__ yt,
                                               const u16* __restrict__ wkb, const u16* __restrict__ wvb,
                                               const u16* __restrict__ wqb,
                                               u16* __restrict__ ktd, u16* __restrict__ vtd,
                                               u16* __restrict__ qtd, int p_base) {
    int bi = blockIdx.x;
    int p = p_base + (bi >> 8);
    int r = bi & 255;
    int et = r & 3, tt = r >> 2;          // et: 128-e tile, tt: 64-t tile (b folded)
    int wv = threadIdx.x >> 6, lane = threadIdx.x & 63;
    int col = lane & 15, q = lane >> 4;
    int b = tt >> 5;
    int t0 = (tt & 31) * 64 + (wv >> 1) * 32;
    int e0 = et * 128 + (wv & 1) * 64;
    const u16* src = (p == 0) ? yt : xt;
    const u16* wb  = (p == 0) ? wqb : (p == 1) ? wkb : wvb;
    const u16* ap0 = src + (size_t)(b * T_ + t0 + col) * CI + q * 8;
    const u16* bp0 = wb + (size_t)(e0 + col) * CI + q * 8;
    f32x4 acc[2][4] = {};
    short8 a0 = ld8(ap0), a1 = ld8(ap0 + 16 * CI);
    short8 b0 = ld8(bp0), b1 = ld8(bp0 + 16 * CI);
    short8 b2 = ld8(bp0 + 32 * CI), b3 = ld8(bp0 + 48 * CI);
#pragma unroll
    for (int ks = 0; ks < 16; ks++) {
        short8 na0, na1, nb0, nb1, nb2, nb3;
        if (ks < 15) {
            na0 = ld8(ap0 + (ks + 1) * 32);
            na1 = ld8(ap0 + 16 * CI + (ks + 1) * 32);
            nb0 = ld8(bp0 + (ks + 1) * 32);
            nb1 = ld8(bp0 + 16 * CI + (ks + 1) * 32);
            nb2 = ld8(bp0 + 32 * CI + (ks + 1) * 32);
            nb3 = ld8(bp0 + 48 * CI + (ks + 1) * 32);
        }
        acc[0][0] = mfma_bf16(a0, b0, acc[0][0]); acc[1][0] = mfma_bf16(a1, b0, acc[1][0]);
        acc[0][1] = mfma_bf16(a0, b1, acc[0][1]); acc[1][1] = mfma_bf16(a1, b1, acc[1][1]);
        acc[0][2] = mfma_bf16(a0, b2, acc[0][2]); acc[1][2] = mfma_bf16(a1, b2, acc[1][2]);
        acc[0][3] = mfma_bf16(a0, b3, acc[0][3]); acc[1][3] = mfma_bf16(a1, b3, acc[1][3]);
        if (ks < 15) {
            a0 = na0; a1 = na1; b0 = nb0; b1 = nb1; b2 = nb2; b3 = nb3;
        }
    }
    // Q gets the softmax scale folded in (sc = 0.125 * log2(e)); K/V unscaled.
    float qs = (p == 0) ? 0.180336880f : 1.0f;
    u16* dst = (p == 0) ? qtd : (p == 1) ? ktd : vtd;
    if (p < 2) {
#pragma unroll
        for (int mt = 0; mt < 2; mt++)
#pragma unroll
            for (int nt = 0; nt < 4; nt++) {
                int e = e0 + nt * 16 + col, h = e >> 6, k = e & 63;
                u16* dp = dst + ((size_t)(b * 8 + h) * T_ + t0 + mt * 16 + q * 4) * DK + k;
                dp[0] = f2bf(acc[mt][nt][0] * qs);
                dp[DK] = f2bf(acc[mt][nt][1] * qs);
                dp[2 * DK] = f2bf(acc[mt][nt][2] * qs);
                dp[3 * DK] = f2bf(acc[mt][nt][3] * qs);
            }
    } else {
#pragma unroll
        for (int mt = 0; mt < 2; mt++)
#pragma unroll
            for (int nt = 0; nt < 4; nt++) {
                int e = e0 + nt * 16 + col, h = e >> 6, v = e & 63;
                uint2 pk;
                pk.x = f2bf(acc[mt][nt][0]) | ((u32)f2bf(acc[mt][nt][1]) << 16);
                pk.y = f2bf(acc[mt][nt][2]) | ((u32)f2bf(acc[mt][nt][3]) << 16);
                *(uint2*)(dst + ((size_t)(b * 8 + h) * DK + v) * T_ + t0 + mt * 16 + q * 4) = pk;
            }
    }
}

// ---------------- flash attention: runtime mask-skip, barrier-free inner loop ----------------
// R13/R14 measured: maskless path (V top-loaded, K ping-pong, no MT loads) = 52.4us.
// Kept verbatim. Masked path (general correctness) = R8 structure.

// masked iteration (mv pre-scaled, Q pre-scaled -> add)
#define ATTN_ITER_M(T0, KC, MC4, MCF, KN, MN4, MNF, TN)  do {                       \
    short8 vb0 = ld8(vbase + (T0));                                                 \
    short8 vb1 = ld8(vbase + 16 * (size_t)T_ + (T0));                               \
    short8 vb2 = ld8(vbase + 32 * (size_t)T_ + (T0));                               \
    short8 vb3 = ld8(vbase + 48 * (size_t)T_ + (T0));                               \
    f32x4 s0g[4], s1g[4];                                                           \
    __builtin_amdgcn_s_setprio(1);                                                  \
    _Pragma("unroll") for (int g = 0; g < 4; g++) {                                 \
        f32x4 z = {};                                                               \
        s0g[g] = mfma_bf16(KC[0], qa[g][0], z);                                     \
        s0g[g] = mfma_bf16(KC[1], qa[g][1], s0g[g]);                                \
        s1g[g] = mfma_bf16(KC[2], qa[g][0], z);                                     \
        s1g[g] = mfma_bf16(KC[3], qa[g][1], s1g[g]);                                \
    }                                                                               \
    __builtin_amdgcn_s_setprio(0);                                                  \
    KN[0] = ld8(kbase + (size_t)(TN) * DK);                                         \
    KN[1] = ld8(kbase + (size_t)(TN) * DK + 32);                                    \
    KN[2] = ld8(kbase + (size_t)((TN) + 4) * DK);                                   \
    KN[3] = ld8(kbase + (size_t)((TN) + 4) * DK + 32);                              \
    if constexpr (MODE == 1) {                                                      \
        _Pragma("unroll") for (int g = 0; g < 4; g++) {                             \
            MN4[g][0] = *(const ushort4*)(mtb[g] + (TN));                           \
            MN4[g][1] = *(const ushort4*)(mtb[g] + (TN) + 4);                       \
        }                                                                           \
    } else {                                                                        \
        _Pragma("unroll") for (int g = 0; g < 4; g++)                               \
        _Pragma("unroll") for (int st = 0; st < 2; st++)                            \
        _Pragma("unroll") for (int rr = 0; rr < 4; rr++)                            \
            MNF[g][st * 4 + rr] =                                                   \
                mbs[g][(size_t)((TN) + q * 8 + st * 4 + rr) * S_] * msc;            \
    }                                                                               \
    _Pragma("unroll") for (int g = 0; g < 4; g++) {                                 \
        bf16x8 pbv;                                                                 \
        float lsum = 0.f;                                                           \
        _Pragma("unroll") for (int i = 0; i < 8; i++) {                             \
            float sv = (i < 4) ? s0g[g][i & 3] : s1g[g][i & 3];                     \
            float mv;                                                               \
            if constexpr (MODE == 1)                                                \
                mv = bf2f(((const u16*)&MC4[g][i >> 2])[i & 3]);                    \
            else                                                                    \
                mv = MCF[g][i];                                                     \
            float p = __builtin_amdgcn_exp2f(sv + mv);                              \
            lsum += p;                                                              \
            pbv[i] = (__bf16)p;                                                     \
        }                                                                           \
        l_part[g] += lsum;                                                          \
        short8 pa = __builtin_bit_cast(short8, pbv);                                \
        __builtin_amdgcn_s_setprio(1);                                              \
        oacc[g][0] = mfma_bf16(vb0, pa, oacc[g][0]);                                \
        oacc[g][1] = mfma_bf16(vb1, pa, oacc[g][1]);                                \
        oacc[g][2] = mfma_bf16(vb2, pa, oacc[g][2]);                                \
        oacc[g][3] = mfma_bf16(vb3, pa, oacc[g][3]);                                \
        __builtin_amdgcn_s_setprio(0);                                              \
    }                                                                               \
} while (0)

// maskless iteration: V top-loaded (R8 register shape), K ping-pong, no mask loads
#define ATTN_ITER_NM(T0, KC, KN, TN)  do {                                          \
    short8 vb0 = ld8(vbase + (T0));                                                 \
    short8 vb1 = ld8(vbase + 16 * (size_t)T_ + (T0));                               \
    short8 vb2 = ld8(vbase + 32 * (size_t)T_ + (T0));                               \
    short8 vb3 = ld8(vbase + 48 * (size_t)T_ + (T0));                               \
    f32x4 s0g[4], s1g[4];                                                           \
    __builtin_amdgcn_s_setprio(1);                                                  \
    _Pragma("unroll") for (int g = 0; g < 4; g++) {                                 \
        f32x4 z = {};                                                               \
        s0g[g] = mfma_bf16(KC[0], qa[g][0], z);                                     \
        s0g[g] = mfma_bf16(KC[1], qa[g][1], s0g[g]);                                \
        s1g[g] = mfma_bf16(KC[2], qa[g][0], z);                                     \
        s1g[g] = mfma_bf16(KC[3], qa[g][1], s1g[g]);                                \
    }                                                                               \
    __builtin_amdgcn_s_setprio(0);                                                  \
    KN[0] = ld8(kbase + (size_t)(TN) * DK);                                         \
    KN[1] = ld8(kbase + (size_t)(TN) * DK + 32);                                    \
    KN[2] = ld8(kbase + (size_t)((TN) + 4) * DK);                                   \
    KN[3] = ld8(kbase + (size_t)((TN) + 4) * DK + 32);                              \
    _Pragma("unroll") for (int g = 0; g < 4; g++) {                                 \
        bf16x8 pbv;                                                                 \
        float lsum = 0.f;                                                           \
        _Pragma("unroll") for (int i = 0; i < 8; i++) {                             \
            float sv = (i < 4) ? s0g[g][i & 3] : s1g[g][i & 3];                     \
            float p = __builtin_amdgcn_exp2f(sv);                                   \
            lsum += p;                                                              \
            pbv[i] = (__bf16)p;                                                     \
        }                                                                           \
        l_part[g] += lsum;                                                          \
        short8 pa = __builtin_bit_cast(short8, pbv);                                \
        __builtin_amdgcn_s_setprio(1);                                              \
        oacc[g][0] = mfma_bf16(vb0, pa, oacc[g][0]);                                \
        oacc[g][1] = mfma_bf16(vb1, pa, oacc[g][1]);                                \
        oacc[g][2] = mfma_bf16(vb2, pa, oacc[g][2]);                                \
        oacc[g][3] = mfma_bf16(vb3, pa, oacc[g][3]);                                \
        __builtin_amdgcn_s_setprio(0);                                              \
    }                                                                               \
} while (0)

template<int MODE>
__global__ __launch_bounds__(512, 2) void k_attn(const u16* __restrict__ kt, const u16* __restrict__ qt,
                                                 const u16* __restrict__ vt, const float* __restrict__ mask,
                                                 const u16* __restrict__ mt, const u32* __restrict__ mflag,
                                                 u16* __restrict__ oa) {
    __shared__ struct { float O[8][16][68]; float L[8][16]; } Sm;   // 35328 B, merge only
    int wv = threadIdx.x >> 6, lane = threadIdx.x & 63;
    int col = lane & 15, q = lane >> 4;
    // XCD-local decode: blocks with blockIdx%8==x cover bh {2x,2x+1}
    int bid = blockIdx.x;
    int j = bid >> 3;
    int bh = (bid & 7) * 2 + (j >> 5);
    int s_base = (j & 31) * 64;
    int sg = s_base + col;
    const int t_begin = wv * (T_ / 8);
    const int t_end = t_begin + (T_ / 8);
    short8 qa[4][2];
#pragma unroll
    for (int g = 0; g < 4; g++) {
        const u16* qp = qt + (size_t)(bh * S_ + sg + g * 16) * DK + q * 8;
        qa[g][0] = ld8(qp);
        qa[g][1] = ld8(qp + 32);
    }
    // K rows permuted so QK output lands in PV B-operand layout
    int tperm = ((col >> 2) << 3) | (col & 3);
    const u16* kbase = kt + (size_t)bh * T_ * DK + (size_t)tperm * DK + q * 8;
    const u16* vbase = vt + (size_t)bh * DK * T_ + (size_t)col * T_ + q * 8;
    float l_part[4] = {0.f, 0.f, 0.f, 0.f};
    f32x4 oacc[4][4] = {};
    const float msc = 0.180336880f;   // 0.125 * log2(e), for the f32-mask fallback

    int use_mask = mflag ? (int)*mflag : 1;

    if (use_mask == 0) {
        // ---- maskless path (mask verified all-zero): no MT loads, V top-loaded ----
        short8 kA[4], kB[4];
        kA[0] = ld8(kbase + (size_t)t_begin * DK);
        kA[1] = ld8(kbase + (size_t)t_begin * DK + 32);
        kA[2] = ld8(kbase + (size_t)(t_begin + 4) * DK);
        kA[3] = ld8(kbase + (size_t)(t_begin + 4) * DK + 32);
        for (int t0 = t_begin; t0 < t_end; t0 += 64) {
            ATTN_ITER_NM(t0, kA, kB, t0 + 32);
            int tn2 = (t0 + 64 < t_end) ? (t0 + 64) : t_begin;   // clamp: last prefetch unused
            ATTN_ITER_NM(t0 + 32, kB, kA, tn2);
        }
    } else {
        // ---- masked path (general correctness; R8 structure) ----
        const float* mbs[4];
        const u16* mtb[4];
#pragma unroll
        for (int g = 0; g < 4; g++) {
            mbs[g] = mask + sg + g * 16;
            mtb[g] = mt + (size_t)(sg + g * 16) * T_ + q * 8;
        }
        short8 kA[4], kB[4];
        ushort4 mA4[4][2], mB4[4][2];
        float mAf[4][8], mBf[4][8];
        kA[0] = ld8(kbase + (size_t)t_begin * DK);
        kA[1] = ld8(kbase + (size_t)t_begin * DK + 32);
        kA[2] = ld8(kbase + (size_t)(t_begin + 4) * DK);
        kA[3] = ld8(kbase + (size_t)(t_begin + 4) * DK + 32);
        if constexpr (MODE == 1) {
#pragma unroll
            for (int g = 0; g < 4; g++) {
                mA4[g][0] = *(const ushort4*)(mtb[g] + t_begin);
                mA4[g][1] = *(const ushort4*)(mtb[g] + t_begin + 4);
            }
        } else {
#pragma unroll
            for (int g = 0; g < 4; g++)
#pragma unroll
                for (int st = 0; st < 2; st++)
#pragma unroll
                    for (int rr = 0; rr < 4; rr++)
                        mAf[g][st * 4 + rr] =
                            mbs[g][(size_t)(t_begin + q * 8 + st * 4 + rr) * S_] * msc;
        }
        for (int t0 = t_begin; t0 < t_end; t0 += 64) {
            ATTN_ITER_M(t0, kA, mA4, mAf, kB, mB4, mBf, t0 + 32);
            int tn2 = (t0 + 64 < t_end) ? (t0 + 64) : t_begin;
            ATTN_ITER_M(t0 + 32, kB, mB4, mBf, kA, mA4, mAf, tn2);
        }
    }

    // l: reduce per-lane partials over q (per-s totals, uniform across q-lanes)
#pragma unroll
    for (int g = 0; g < 4; g++) {
        float lr = l_part[g];
        lr += __shfl_xor(lr, 16);
        lr += __shfl_xor(lr, 32);
        l_part[g] = lr;
    }

    // ---- merge of the 8 per-wave T-partials: O = Sum(O_c) / Sum(l_c), per 16-s group ----
    int b = bh >> 3, h = bh & 7;
    __syncthreads();
#pragma unroll
    for (int g = 0; g < 4; g++) {
#pragma unroll
        for (int nt = 0; nt < 4; nt++)
            *(f32x4*)&Sm.O[wv][col][nt * 16 + q * 4] = oacc[g][nt];
        if (lane < 16)
            Sm.L[wv][lane] = l_part[g];
        __syncthreads();
        // 1024 outputs (16 s x 64 v), 512 threads -> 2 each
#pragma unroll
        for (int e = 0; e < 2; e++) {
            int f = (int)threadIdx.x + e * 512;
            int s = f >> 6, v = f & 63;
            float acc = 0.f, lt = 0.f;
#pragma unroll
            for (int c = 0; c < 8; c++) {
                acc += Sm.O[c][s][v];
                lt += Sm.L[c][s];
            }
            oa[(size_t)(b * S_ + s_base + g * 16 + s) * E_ + h * DK + v] = f2bf(acc / lt);
        }
        __syncthreads();   // O/L reused by next group
    }
}

// ---------------- final GEMM (R11 geometry: 64s x 64o, grid 512, pipelined) ----------------
// wave tile 32s x 32o
__global__ __launch_bounds__(256) void k_final(const u16* __restrict__ oa, const u16* __restrict__ wfb,
                                               const float* __restrict__ bias, float* __restrict__ out) {
    int bi = blockIdx.x;
    int et = bi & 7, tt = bi >> 3;
    int wv = threadIdx.x >> 6, lane = threadIdx.x & 63;
    int col = lane & 15, q = lane >> 4;
    int b = tt >> 5;
    int s0 = (tt & 31) * 64 + (wv >> 1) * 32;
    int o0 = et * 64 + (wv & 1) * 32;
    const u16* ap0 = oa + (size_t)(b * S_ + s0 + col) * E_ + q * 8;
    const u16* bp0 = wfb + (size_t)(o0 + col) * E_ + q * 8;
    f32x4 acc[2][2] = {};
    short8 a0 = ld8(ap0), a1 = ld8(ap0 + 16 * E_);
    short8 b0 = ld8(bp0), b1 = ld8(bp0 + 16 * E_);
#pragma unroll
    for (int ks = 0; ks < 16; ks++) {
        short8 na0, na1, nb0, nb1;
        if (ks < 15) {
            na0 = ld8(ap0 + (ks + 1) * 32);
            na1 = ld8(ap0 + 16 * E_ + (ks + 1) * 32);
            nb0 = ld8(bp0 + (ks + 1) * 32);
            nb1 = ld8(bp0 + 16 * E_ + (ks + 1) * 32);
        }
        acc[0][0] = mfma_bf16(a0, b0, acc[0][0]); acc[1][0] = mfma_bf16(a1, b0, acc[1][0]);
        acc[0][1] = mfma_bf16(a0, b1, acc[0][1]); acc[1][1] = mfma_bf16(a1, b1, acc[1][1]);
        if (ks < 15) {
            a0 = na0; a1 = na1; b0 = nb0; b1 = nb1;
        }
    }
#pragma unroll
    for (int mt = 0; mt < 2; mt++)
#pragma unroll
        for (int nt = 0; nt < 2; nt++) {
            int o = o0 + nt * 16 + col;
            float bn = bias[o];
#pragma unroll
            for (int r = 0; r < 4; r++) {
                int s = s0 + mt * 16 + q * 4 + r;
                out[(size_t)(b * S_ + s) * CO + o] = acc[mt][nt][r] + bn;
            }
        }
}

extern "C" void kernel_launch(void* const* d_in, const int* in_sizes, int n_in,
                              void* d_out, int out_size, void* d_ws, size_t ws_size,
                              hipStream_t stream) {
    const float* x    = (const float*)d_in[0];
    const float* y    = (const float*)d_in[1];
    const float* mask = (const float*)d_in[2];
    const float* Wk   = (const float*)d_in[3];
    const float* Wv   = (const float*)d_in[4];
    const float* Wq   = (const float*)d_in[5];
    const float* Wf   = (const float*)d_in[6];
    const float* bias = (const float*)d_in[7];
    float* out = (float*)d_out;

    // Layout (u16 units): 18 MiB core + 8 MiB MT + 4 MiB separate VT + mask flag.
    u16* ws = (u16*)d_ws;
    u16* XT  = ws;                 // x^T bf16; reused as OA after projections
    u16* YT  = XT + 2097152;       // y^T bf16; fallback VT alias
    u16* WKB = YT + 2097152;
    u16* WVB = WKB + 262144;
    u16* WQB = WVB + 262144;
    u16* WFB = WQB + 262144;
    u16* KT  = WFB + 262144;
    u16* QT  = KT + 2097152;       // end = 18 MiB
    u16* MT  = QT + 2097152;       // mask^T bf16 pre-scaled, end = 26 MiB
    u16* VTs = MT + 4194304;       // separate V, end = 30 MiB
    u32* MF  = (u32*)(VTs + 2097152);  // mask-nonzero flag, at 30 MiB
    u16* OA  = XT;                 // alias: XT dead after K/V proj

    int use_mt   = (ws_size >= (size_t)27262976) ? 1 : 0;   // 26 MiB for MT
    int has_vt   = (ws_size >= (size_t)31457280) ? 1 : 0;   // 30 MiB for separate VT
    int has_flag = (ws_size >= (size_t)31457344) ? 1 : 0;   // 30 MiB + flag word
    u16* VT = has_vt ? VTs : YT;
    u32* MFp = (use_mt && has_flag) ? MF : (u32*)nullptr;

    if (MFp)
        hipMemsetAsync(MFp, 0, 4, stream);
    // single prep launch: transpose (1024 blocks) + weight cvt (512) + mask^T (1024)
    k_prep<<<use_mt ? 2560 : 1536, 256, 0, stream>>>(x, y, Wk, Wv, Wq, Wf, mask,
                                                     XT, YT, WKB, WVB, WQB, WFB, MT, MFp);
    if (has_vt) {
        // single fused launch: Q (reads YT), K, V (writes separate VTs)
        k_proj3<<<768, 256, 0, stream>>>(XT, YT, WKB, WVB, WQB, KT, VT, QT, 0);
    } else {
        // launch 1: Q (reads YT) + K; launch 2: V (writes VT == YT, safe after launch 1)
        k_proj3<<<512, 256, 0, stream>>>(XT, YT, WKB, WVB, WQB, KT, VT, QT, 0);
        k_proj3<<<256, 256, 0, stream>>>(XT, YT, WKB, WVB, WQB, KT, VT, QT, 2);
    }
    if (use_mt)
        k_attn<1><<<512, 512, 0, stream>>>(KT, QT, VT, mask, MT, MFp, OA);
    else
        k_attn<0><<<512, 512, 0, stream>>>(KT, QT, VT, mask, MT, MFp, OA);
    k_final<<<512, 256, 0, stream>>>(OA, WFB, bias, out);
}

// Round 17
// 171.228 us; speedup vs baseline: 1.1416x; 1.1416x over previous
//
#include <hip/hip_runtime.h>
#include <stdint.h>

typedef unsigned short u16;
typedef unsigned int u32;

#define B_    2
#define DK    64
#define T_    2048
#define S_    2048
#define CI    512
#define CO    512
#define E_    512

typedef short  short8 __attribute__((ext_vector_type(8)));
typedef __bf16 bf16x8 __attribute__((ext_vector_type(8)));
typedef float  f32x4  __attribute__((ext_vector_type(4)));

static __device__ __forceinline__ u16 f2bf(float f) {
    return __builtin_bit_cast(u16, (__bf16)f);
}

static __device__ __forceinline__ float bf2f(u16 h) {
    return __uint_as_float((u32)h << 16);
}

static __device__ __forceinline__ short8 ld8(const u16* p) {
    return *(const short8*)p;
}

static __device__ __forceinline__ f32x4 mfma_bf16(short8 a, short8 b, f32x4 c) {
    return __builtin_amdgcn_mfma_f32_16x16x32_bf16(
        __builtin_bit_cast(bf16x8, a), __builtin_bit_cast(bf16x8, b), c, 0, 0, 0);
}

// ---------------- fused prep (vectorized): x/y transpose + weight cvt + mask^T ----------------
__global__ __launch_bounds__(256) void k_prep(const float* __restrict__ x, const float* __restrict__ y,
                                              const float* __restrict__ wk, const float* __restrict__ wv,
                                              const float* __restrict__ wq, const float* __restrict__ wf,
                                              const float* __restrict__ mask,
                                              u16* __restrict__ xt, u16* __restrict__ yt,
                                              u16* __restrict__ wkb, u16* __restrict__ wvb,
                                              u16* __restrict__ wqb, u16* __restrict__ wfb,
                                              u16* __restrict__ mt, u32* __restrict__ mflag) {
    __shared__ float tile[64][65];
    int bid = blockIdx.x;
    if (bid < 1024) {
        // transpose + cvt: src[b][i][t] f32 -> dst[b][t][i] bf16, 64x64 tile
        int bx = bid & 31, by = (bid >> 5) & 7, bz = bid >> 8;
        int tsel = bz >> 1, b = bz & 1;
        const float* src = tsel ? y : x;
        u16* dst = tsel ? yt : xt;
        int t0 = bx * 64, i0 = by * 64;
        int tx = threadIdx.x & 15, ty = threadIdx.x >> 4;
#pragma unroll
        for (int r = 0; r < 4; r++) {
            int i = ty + r * 16;
            *(float4*)&tile[i][tx * 4] =
                *(const float4*)(src + (size_t)(b * CI + i0 + i) * T_ + t0 + tx * 4);
        }
        __syncthreads();
        int tx2 = threadIdx.x & 7, ty2 = threadIdx.x >> 3;
#pragma unroll
        for (int r = 0; r < 2; r++) {
            int t = ty2 + r * 32;
            short8 o;
#pragma unroll
            for (int j = 0; j < 8; j++)
                o[j] = (short)f2bf(tile[tx2 * 8 + j][t]);
            *(short8*)(dst + (size_t)(b * T_ + t0 + t) * CI + i0 + tx2 * 8) = o;
        }
    } else if (bid < 1536) {
        // weight cvt, 8 elems/thread
        int off = ((bid - 1024) * 256 + threadIdx.x) * 8;
        int w = off >> 18, r = off & 262143;
        const float* s = (w == 0) ? wk : (w == 1) ? wv : (w == 2) ? wq : wf;
        u16* d = (w == 0) ? wkb : (w == 1) ? wvb : (w == 2) ? wqb : wfb;
        float4 a0 = *(const float4*)(s + r);
        float4 a1 = *(const float4*)(s + r + 4);
        short8 o;
        o[0] = f2bf(a0.x); o[1] = f2bf(a0.y); o[2] = f2bf(a0.z); o[3] = f2bf(a0.w);
        o[4] = f2bf(a1.x); o[5] = f2bf(a1.y); o[6] = f2bf(a1.z); o[7] = f2bf(a1.w);
        *(short8*)(d + r) = o;
    } else {
        // mask transpose + pre-scale; detect any-nonzero
        int mb = bid - 1536;
        int bx = mb & 31, by = mb >> 5;
        int t0 = bx * 64, s0 = by * 64;
        int tx = threadIdx.x & 15, ty = threadIdx.x >> 4;
        const float msc = 0.125f * 1.44269504088896f;
        bool nz = false;
#pragma unroll
        for (int r = 0; r < 4; r++) {
            int t = ty + r * 16;
            float4 v = *(const float4*)(mask + (size_t)(t0 + t) * S_ + s0 + tx * 4);
            nz |= (v.x != 0.0f) | (v.y != 0.0f) | (v.z != 0.0f) | (v.w != 0.0f);
            *(float4*)&tile[t][tx * 4] = v;
        }
        if (mflag && __any(nz) && (threadIdx.x & 63) == 0)
            atomicOr(mflag, 1u);
        __syncthreads();
        int tx2 = threadIdx.x & 7, ty2 = threadIdx.x >> 3;
#pragma unroll
        for (int r = 0; r < 2; r++) {
            int s = ty2 + r * 32;
            short8 o;
#pragma unroll
            for (int j = 0; j < 8; j++)
                o[j] = (short)f2bf(tile[tx2 * 8 + j][s] * msc);
            *(short8*)(mt + (size_t)(s0 + s) * T_ + t0 + tx2 * 8) = o;
        }
    }
}

// ---------------- fused projection GEMMs (64t x 128e, pipelined) ----------------
// attn's K/V loads scattered across ~250 cache lines per iter (V: 4KB row stride).
// Fix at the producer: K and V stored FRAGMENT-MAJOR, in exactly the per-wave MFMA
// operand order attn consumes, so each attn ld8 is 64 lanes x 16B CONTIGUOUS (1KB).
//   KF[bh][t/32][piece:4][lane:64][8]: piece p=(thi<<1)|khi; lane l: trel =
//     tperm(l&15)+(p>=2?4:0), k=(p&1)*32+(l>>4)*8+j   (tperm(c)=((c>>2)<<3)|(c&3))
//   VF[bh][t/32][nt:4][lane:64][8]: v=nt*16+(l&15), trel=(l>>4)*8+j
// p = p_base + (blockIdx.x>>8): 0=Q (yt->QT, pre-scaled by sc), 1=K->KF, 2=V->VF.
__global__ __launch_bounds__(256) void k_proj3(const u16* __restrict__ xt, const u16* __restrict__ yt,
                                               const u16* __restrict__ wkb, const u16* __restrict__ wvb,
                                               const u16* __restrict__ wqb,
                                               u16* __restrict__ kfd, u16* __restrict__ vfd,
                                               u16* __restrict__ qtd, int p_base) {
    int bi = blockIdx.x;
    int p = p_base + (bi >> 8);
    int r = bi & 255;
    int et = r & 3, tt = r >> 2;
    int wv = threadIdx.x >> 6, lane = threadIdx.x & 63;
    int col = lane & 15, q = lane >> 4;
    int b = tt >> 5;
    int t0 = (tt & 31) * 64 + (wv >> 1) * 32;
    int e0 = et * 128 + (wv & 1) * 64;
    const u16* src = (p == 0) ? yt : xt;
    const u16* wb  = (p == 0) ? wqb : (p == 1) ? wkb : wvb;
    const u16* ap0 = src + (size_t)(b * T_ + t0 + col) * CI + q * 8;
    const u16* bp0 = wb + (size_t)(e0 + col) * CI + q * 8;
    f32x4 acc[2][4] = {};
    short8 a0 = ld8(ap0), a1 = ld8(ap0 + 16 * CI);
    short8 b0 = ld8(bp0), b1 = ld8(bp0 + 16 * CI);
    short8 b2 = ld8(bp0 + 32 * CI), b3 = ld8(bp0 + 48 * CI);
#pragma unroll
    for (int ks = 0; ks < 16; ks++) {
        short8 na0, na1, nb0, nb1, nb2, nb3;
        if (ks < 15) {
            na0 = ld8(ap0 + (ks + 1) * 32);
            na1 = ld8(ap0 + 16 * CI + (ks + 1) * 32);
            nb0 = ld8(bp0 + (ks + 1) * 32);
            nb1 = ld8(bp0 + 16 * CI + (ks + 1) * 32);
            nb2 = ld8(bp0 + 32 * CI + (ks + 1) * 32);
            nb3 = ld8(bp0 + 48 * CI + (ks + 1) * 32);
        }
        acc[0][0] = mfma_bf16(a0, b0, acc[0][0]); acc[1][0] = mfma_bf16(a1, b0, acc[1][0]);
        acc[0][1] = mfma_bf16(a0, b1, acc[0][1]); acc[1][1] = mfma_bf16(a1, b1, acc[1][1]);
        acc[0][2] = mfma_bf16(a0, b2, acc[0][2]); acc[1][2] = mfma_bf16(a1, b2, acc[1][2]);
        acc[0][3] = mfma_bf16(a0, b3, acc[0][3]); acc[1][3] = mfma_bf16(a1, b3, acc[1][3]);
        if (ks < 15) {
            a0 = na0; a1 = na1; b0 = nb0; b1 = nb1; b2 = nb2; b3 = nb3;
        }
    }
    const float qs = 0.180336880f;   // 0.125 * log2(e), folded into Q
    if (p == 0) {
#pragma unroll
        for (int mt = 0; mt < 2; mt++)
#pragma unroll
            for (int nt = 0; nt < 4; nt++) {
                int e = e0 + nt * 16 + col, h = e >> 6, k = e & 63;
                u16* dp = qtd + ((size_t)(b * 8 + h) * T_ + t0 + mt * 16 + q * 4) * DK + k;
                dp[0] = f2bf(acc[mt][nt][0] * qs);
                dp[DK] = f2bf(acc[mt][nt][1] * qs);
                dp[2 * DK] = f2bf(acc[mt][nt][2] * qs);
                dp[3 * DK] = f2bf(acc[mt][nt][3] * qs);
            }
    } else if (p == 1) {
        // K -> fragment-major KF. Value acc[mt][nt][r]: t = t0+mt*16+q*4+r, k = e&63.
        int ttk = t0 >> 5;
#pragma unroll
        for (int mt = 0; mt < 2; mt++) {
            int cb = (mt * 2 + (q >> 1)) << 2;
#pragma unroll
            for (int nt = 0; nt < 4; nt++) {
                int e = e0 + nt * 16 + col, h = e >> 6, k = e & 63;
                int pp = ((q & 1) << 1) | (k >> 5);
                int lf = (((k & 31) >> 3) << 4) + cb;
                u16* dp = kfd + ((((size_t)(b * 8 + h) * 64 + ttk) * 4 + pp) * 64 + lf) * 8 + (k & 7);
                dp[0]  = f2bf(acc[mt][nt][0]);
                dp[8]  = f2bf(acc[mt][nt][1]);
                dp[16] = f2bf(acc[mt][nt][2]);
                dp[24] = f2bf(acc[mt][nt][3]);
            }
        }
    } else {
        // V -> fragment-major VF. Value acc[mt][nt][r]: t = t0+mt*16+q*4+r, v = e&63.
        int ttv = t0 >> 5;
        int j0 = (q & 1) * 4;
#pragma unroll
        for (int mt = 0; mt < 2; mt++) {
            int lf = col | ((mt * 2 + (q >> 1)) << 4);
#pragma unroll
            for (int nt = 0; nt < 4; nt++) {
                int e = e0 + nt * 16 + col, h = e >> 6;
                uint2 pk;
                pk.x = f2bf(acc[mt][nt][0]) | ((u32)f2bf(acc[mt][nt][1]) << 16);
                pk.y = f2bf(acc[mt][nt][2]) | ((u32)f2bf(acc[mt][nt][3]) << 16);
                *(uint2*)(vfd + ((((size_t)(b * 8 + h) * 64 + ttv) * 4 + nt) * 64 + lf) * 8 + j0) = pk;
            }
        }
    }
}

// ---------------- flash attention: fragment-coalesced K/V, runtime mask-skip ----------------
// All K/V ld8 are now 64x16B contiguous (fragment-major). Tile index TT = t/32.

// masked iteration (mv pre-scaled, Q pre-scaled -> add)
#define ATTN_ITER_M(TT, KC, MC4, MCF, KN, MN4, MNF, TTN)  do {                      \
    short8 vb0 = ld8(vfb + ((TT) * 4 + 0) * 512);                                   \
    short8 vb1 = ld8(vfb + ((TT) * 4 + 1) * 512);                                   \
    short8 vb2 = ld8(vfb + ((TT) * 4 + 2) * 512);                                   \
    short8 vb3 = ld8(vfb + ((TT) * 4 + 3) * 512);                                   \
    f32x4 s0g[4], s1g[4];                                                           \
    __builtin_amdgcn_s_setprio(1);                                                  \
    _Pragma("unroll") for (int g = 0; g < 4; g++) {                                 \
        f32x4 z = {};                                                               \
        s0g[g] = mfma_bf16(KC[0], qa[g][0], z);                                     \
        s0g[g] = mfma_bf16(KC[1], qa[g][1], s0g[g]);                                \
        s1g[g] = mfma_bf16(KC[2], qa[g][0], z);                                     \
        s1g[g] = mfma_bf16(KC[3], qa[g][1], s1g[g]);                                \
    }                                                                               \
    __builtin_amdgcn_s_setprio(0);                                                  \
    KN[0] = ld8(kfb + ((TTN) * 4 + 0) * 512);                                       \
    KN[1] = ld8(kfb + ((TTN) * 4 + 1) * 512);                                       \
    KN[2] = ld8(kfb + ((TTN) * 4 + 2) * 512);                                       \
    KN[3] = ld8(kfb + ((TTN) * 4 + 3) * 512);                                       \
    if constexpr (MODE == 1) {                                                      \
        _Pragma("unroll") for (int g = 0; g < 4; g++) {                             \
            MN4[g][0] = *(const ushort4*)(mtb[g] + (TTN) * 32);                     \
            MN4[g][1] = *(const ushort4*)(mtb[g] + (TTN) * 32 + 4);                 \
        }                                                                           \
    } else {                                                                        \
        _Pragma("unroll") for (int g = 0; g < 4; g++)                               \
        _Pragma("unroll") for (int st = 0; st < 2; st++)                            \
        _Pragma("unroll") for (int rr = 0; rr < 4; rr++)                            \
            MNF[g][st * 4 + rr] =                                                   \
                mbs[g][(size_t)((TTN) * 32 + q * 8 + st * 4 + rr) * S_] * msc;      \
    }                                                                               \
    _Pragma("unroll") for (int g = 0; g < 4; g++) {                                 \
        bf16x8 pbv;                                                                 \
        float lsum = 0.f;                                                           \
        _Pragma("unroll") for (int i = 0; i < 8; i++) {                             \
            float sv = (i < 4) ? s0g[g][i & 3] : s1g[g][i & 3];                     \
            float mv;                                                               \
            if constexpr (MODE == 1)                                                \
                mv = bf2f(((const u16*)&MC4[g][i >> 2])[i & 3]);                    \
            else                                                                    \
                mv = MCF[g][i];                                                     \
            float p = __builtin_amdgcn_exp2f(sv + mv);                              \
            lsum += p;                                                              \
            pbv[i] = (__bf16)p;                                                     \
        }                                                                           \
        l_part[g] += lsum;                                                          \
        short8 pa = __builtin_bit_cast(short8, pbv);                                \
        __builtin_amdgcn_s_setprio(1);                                              \
        oacc[g][0] = mfma_bf16(vb0, pa, oacc[g][0]);                                \
        oacc[g][1] = mfma_bf16(vb1, pa, oacc[g][1]);                                \
        oacc[g][2] = mfma_bf16(vb2, pa, oacc[g][2]);                                \
        oacc[g][3] = mfma_bf16(vb3, pa, oacc[g][3]);                                \
        __builtin_amdgcn_s_setprio(0);                                              \
    }                                                                               \
} while (0)

// maskless iteration: V top-loaded, K ping-pong, no mask loads
#define ATTN_ITER_NM(TT, KC, KN, TTN)  do {                                         \
    short8 vb0 = ld8(vfb + ((TT) * 4 + 0) * 512);                                   \
    short8 vb1 = ld8(vfb + ((TT) * 4 + 1) * 512);                                   \
    short8 vb2 = ld8(vfb + ((TT) * 4 + 2) * 512);                                   \
    short8 vb3 = ld8(vfb + ((TT) * 4 + 3) * 512);                                   \
    f32x4 s0g[4], s1g[4];                                                           \
    __builtin_amdgcn_s_setprio(1);                                                  \
    _Pragma("unroll") for (int g = 0; g < 4; g++) {                                 \
        f32x4 z = {};                                                               \
        s0g[g] = mfma_bf16(KC[0], qa[g][0], z);                                     \
        s0g[g] = mfma_bf16(KC[1], qa[g][1], s0g[g]);                                \
        s1g[g] = mfma_bf16(KC[2], qa[g][0], z);                                     \
        s1g[g] = mfma_bf16(KC[3], qa[g][1], s1g[g]);                                \
    }                                                                               \
    __builtin_amdgcn_s_setprio(0);                                                  \
    KN[0] = ld8(kfb + ((TTN) * 4 + 0) * 512);                                       \
    KN[1] = ld8(kfb + ((TTN) * 4 + 1) * 512);                                       \
    KN[2] = ld8(kfb + ((TTN) * 4 + 2) * 512);                                       \
    KN[3] = ld8(kfb + ((TTN) * 4 + 3) * 512);                                       \
    _Pragma("unroll") for (int g = 0; g < 4; g++) {                                 \
        bf16x8 pbv;                                                                 \
        float lsum = 0.f;                                                           \
        _Pragma("unroll") for (int i = 0; i < 8; i++) {                             \
            float sv = (i < 4) ? s0g[g][i & 3] : s1g[g][i & 3];                     \
            float p = __builtin_amdgcn_exp2f(sv);                                   \
            lsum += p;                                                              \
            pbv[i] = (__bf16)p;                                                     \
        }                                                                           \
        l_part[g] += lsum;                                                          \
        short8 pa = __builtin_bit_cast(short8, pbv);                                \
        __builtin_amdgcn_s_setprio(1);                                              \
        oacc[g][0] = mfma_bf16(vb0, pa, oacc[g][0]);                                \
        oacc[g][1] = mfma_bf16(vb1, pa, oacc[g][1]);                                \
        oacc[g][2] = mfma_bf16(vb2, pa, oacc[g][2]);                                \
        oacc[g][3] = mfma_bf16(vb3, pa, oacc[g][3]);                                \
        __builtin_amdgcn_s_setprio(0);                                              \
    }                                                                               \
} while (0)

template<int MODE>
__global__ __launch_bounds__(512, 2) void k_attn(const u16* __restrict__ kf, const u16* __restrict__ qt,
                                                 const u16* __restrict__ vf, const float* __restrict__ mask,
                                                 const u16* __restrict__ mt, const u32* __restrict__ mflag,
                                                 u16* __restrict__ oa) {
    __shared__ struct { float O[8][16][68]; float L[8][16]; } Sm;   // merge only
    int wv = threadIdx.x >> 6, lane = threadIdx.x & 63;
    int col = lane & 15, q = lane >> 4;
    int bid = blockIdx.x;
    int j = bid >> 3;
    int bh = (bid & 7) * 2 + (j >> 5);
    int s_base = (j & 31) * 64;
    int sg = s_base + col;
    const int tt_begin = wv * 8;          // 8 x 32-t tiles per wave (T/8 = 256)
    const int tt_end = tt_begin + 8;
    short8 qa[4][2];
#pragma unroll
    for (int g = 0; g < 4; g++) {
        const u16* qp = qt + (size_t)(bh * S_ + sg + g * 16) * DK + q * 8;
        qa[g][0] = ld8(qp);
        qa[g][1] = ld8(qp + 32);
    }
    // fragment bases: per-lane offset baked in; tile stride = 4*512 u16, bh stride = 64 tiles
    const u16* kfb = kf + (size_t)bh * 131072 + lane * 8;
    const u16* vfb = vf + (size_t)bh * 131072 + lane * 8;
    float l_part[4] = {0.f, 0.f, 0.f, 0.f};
    f32x4 oacc[4][4] = {};
    const float msc = 0.180336880f;   // for the f32-mask fallback

    int use_mask = mflag ? (int)*mflag : 1;

    if (use_mask == 0) {
        short8 kA[4], kB[4];
        kA[0] = ld8(kfb + (tt_begin * 4 + 0) * 512);
        kA[1] = ld8(kfb + (tt_begin * 4 + 1) * 512);
        kA[2] = ld8(kfb + (tt_begin * 4 + 2) * 512);
        kA[3] = ld8(kfb + (tt_begin * 4 + 3) * 512);
        for (int tt = tt_begin; tt < tt_end; tt += 2) {
            ATTN_ITER_NM(tt, kA, kB, tt + 1);
            int ttn2 = (tt + 2 < tt_end) ? (tt + 2) : tt_begin;
            ATTN_ITER_NM(tt + 1, kB, kA, ttn2);
        }
    } else {
        const float* mbs[4];
        const u16* mtb[4];
#pragma unroll
        for (int g = 0; g < 4; g++) {
            mbs[g] = mask + sg + g * 16;
            mtb[g] = mt + (size_t)(sg + g * 16) * T_ + q * 8;
        }
        short8 kA[4], kB[4];
        ushort4 mA4[4][2], mB4[4][2];
        float mAf[4][8], mBf[4][8];
        kA[0] = ld8(kfb + (tt_begin * 4 + 0) * 512);
        kA[1] = ld8(kfb + (tt_begin * 4 + 1) * 512);
        kA[2] = ld8(kfb + (tt_begin * 4 + 2) * 512);
        kA[3] = ld8(kfb + (tt_begin * 4 + 3) * 512);
        if constexpr (MODE == 1) {
#pragma unroll
            for (int g = 0; g < 4; g++) {
                mA4[g][0] = *(const ushort4*)(mtb[g] + tt_begin * 32);
                mA4[g][1] = *(const ushort4*)(mtb[g] + tt_begin * 32 + 4);
            }
        } else {
#pragma unroll
            for (int g = 0; g < 4; g++)
#pragma unroll
                for (int st = 0; st < 2; st++)
#pragma unroll
                    for (int rr = 0; rr < 4; rr++)
                        mAf[g][st * 4 + rr] =
                            mbs[g][(size_t)(tt_begin * 32 + q * 8 + st * 4 + rr) * S_] * msc;
        }
        for (int tt = tt_begin; tt < tt_end; tt += 2) {
            ATTN_ITER_M(tt, kA, mA4, mAf, kB, mB4, mBf, tt + 1);
            int ttn2 = (tt + 2 < tt_end) ? (tt + 2) : tt_begin;
            ATTN_ITER_M(tt + 1, kB, mB4, mBf, kA, mA4, mAf, ttn2);
        }
    }

    // l: reduce per-lane partials over q
#pragma unroll
    for (int g = 0; g < 4; g++) {
        float lr = l_part[g];
        lr += __shfl_xor(lr, 16);
        lr += __shfl_xor(lr, 32);
        l_part[g] = lr;
    }

    // ---- merge of the 8 per-wave T-partials: O = Sum(O_c) / Sum(l_c) ----
    int b = bh >> 3, h = bh & 7;
    __syncthreads();
#pragma unroll
    for (int g = 0; g < 4; g++) {
#pragma unroll
        for (int nt = 0; nt < 4; nt++)
            *(f32x4*)&Sm.O[wv][col][nt * 16 + q * 4] = oacc[g][nt];
        if (lane < 16)
            Sm.L[wv][lane] = l_part[g];
        __syncthreads();
#pragma unroll
        for (int e = 0; e < 2; e++) {
            int f = (int)threadIdx.x + e * 512;
            int s = f >> 6, v = f & 63;
            float acc = 0.f, lt = 0.f;
#pragma unroll
            for (int c = 0; c < 8; c++) {
                acc += Sm.O[c][s][v];
                lt += Sm.L[c][s];
            }
            oa[(size_t)(b * S_ + s_base + g * 16 + s) * E_ + h * DK + v] = f2bf(acc / lt);
        }
        __syncthreads();
    }
}

// ---------------- final GEMM (64s x 64o, grid 512, pipelined) ----------------
__global__ __launch_bounds__(256) void k_final(const u16* __restrict__ oa, const u16* __restrict__ wfb,
                                               const float* __restrict__ bias, float* __restrict__ out) {
    int bi = blockIdx.x;
    int et = bi & 7, tt = bi >> 3;
    int wv = threadIdx.x >> 6, lane = threadIdx.x & 63;
    int col = lane & 15, q = lane >> 4;
    int b = tt >> 5;
    int s0 = (tt & 31) * 64 + (wv >> 1) * 32;
    int o0 = et * 64 + (wv & 1) * 32;
    const u16* ap0 = oa + (size_t)(b * S_ + s0 + col) * E_ + q * 8;
    const u16* bp0 = wfb + (size_t)(o0 + col) * E_ + q * 8;
    f32x4 acc[2][2] = {};
    short8 a0 = ld8(ap0), a1 = ld8(ap0 + 16 * E_);
    short8 b0 = ld8(bp0), b1 = ld8(bp0 + 16 * E_);
#pragma unroll
    for (int ks = 0; ks < 16; ks++) {
        short8 na0, na1, nb0, nb1;
        if (ks < 15) {
            na0 = ld8(ap0 + (ks + 1) * 32);
            na1 = ld8(ap0 + 16 * E_ + (ks + 1) * 32);
            nb0 = ld8(bp0 + (ks + 1) * 32);
            nb1 = ld8(bp0 + 16 * E_ + (ks + 1) * 32);
        }
        acc[0][0] = mfma_bf16(a0, b0, acc[0][0]); acc[1][0] = mfma_bf16(a1, b0, acc[1][0]);
        acc[0][1] = mfma_bf16(a0, b1, acc[0][1]); acc[1][1] = mfma_bf16(a1, b1, acc[1][1]);
        if (ks < 15) {
            a0 = na0; a1 = na1; b0 = nb0; b1 = nb1;
        }
    }
#pragma unroll
    for (int mt = 0; mt < 2; mt++)
#pragma unroll
        for (int nt = 0; nt < 2; nt++) {
            int o = o0 + nt * 16 + col;
            float bn = bias[o];
#pragma unroll
            for (int r = 0; r < 4; r++) {
                int s = s0 + mt * 16 + q * 4 + r;
                out[(size_t)(b * S_ + s) * CO + o] = acc[mt][nt][r] + bn;
            }
        }
}

extern "C" void kernel_launch(void* const* d_in, const int* in_sizes, int n_in,
                              void* d_out, int out_size, void* d_ws, size_t ws_size,
                              hipStream_t stream) {
    const float* x    = (const float*)d_in[0];
    const float* y    = (const float*)d_in[1];
    const float* mask = (const float*)d_in[2];
    const float* Wk   = (const float*)d_in[3];
    const float* Wv   = (const float*)d_in[4];
    const float* Wq   = (const float*)d_in[5];
    const float* Wf   = (const float*)d_in[6];
    const float* bias = (const float*)d_in[7];
    float* out = (float*)d_out;

    u16* ws = (u16*)d_ws;
    u16* XT  = ws;                 // x^T bf16; reused as OA after projections
    u16* YT  = XT + 2097152;       // y^T bf16; fallback VF alias
    u16* WKB = YT + 2097152;
    u16* WVB = WKB + 262144;
    u16* WQB = WVB + 262144;
    u16* WFB = WQB + 262144;
    u16* KF  = WFB + 262144;       // fragment-major K, 4 MiB
    u16* QT  = KF + 2097152;       // end = 18 MiB
    u16* MT  = QT + 2097152;       // mask^T bf16 pre-scaled, end = 26 MiB
    u16* VFs = MT + 4194304;       // fragment-major V, end = 30 MiB
    u32* MF  = (u32*)(VFs + 2097152);
    u16* OA  = XT;

    int use_mt   = (ws_size >= (size_t)27262976) ? 1 : 0;
    int has_vt   = (ws_size >= (size_t)31457280) ? 1 : 0;
    int has_flag = (ws_size >= (size_t)31457344) ? 1 : 0;
    u16* VF = has_vt ? VFs : YT;
    u32* MFp = (use_mt && has_flag) ? MF : (u32*)nullptr;

    if (MFp)
        (void)hipMemsetAsync(MFp, 0, 4, stream);
    k_prep<<<use_mt ? 2560 : 1536, 256, 0, stream>>>(x, y, Wk, Wv, Wq, Wf, mask,
                                                     XT, YT, WKB, WVB, WQB, WFB, MT, MFp);
    if (has_vt) {
        k_proj3<<<768, 256, 0, stream>>>(XT, YT, WKB, WVB, WQB, KF, VF, QT, 0);
    } else {
        k_proj3<<<512, 256, 0, stream>>>(XT, YT, WKB, WVB, WQB, KF, VF, QT, 0);
        k_proj3<<<256, 256, 0, stream>>>(XT, YT, WKB, WVB, WQB, KF, VF, QT, 2);
    }
    if (use_mt)
        k_attn<1><<<512, 512, 0, stream>>>(KF, QT, VF, mask, MT, MFp, OA);
    else
        k_attn<0><<<512, 512, 0, stream>>>(KF, QT, VF, mask, MT, MFp, OA);
    k_final<<<512, 256, 0, stream>>>(OA, WFB, bias, out);
}

// Round 18
// 166.605 us; speedup vs baseline: 1.1733x; 1.0277x over previous
//
#include <hip/hip_runtime.h>
#include <stdint.h>

typedef unsigned short u16;
typedef unsigned int u32;

#define B_    2
#define DK    64
#define T_    2048
#define S_    2048
#define CI    512
#define CO    512
#define E_    512

typedef short  short8 __attribute__((ext_vector_type(8)));
typedef __bf16 bf16x8 __attribute__((ext_vector_type(8)));
typedef float  f32x4  __attribute__((ext_vector_type(4)));

static __device__ __forceinline__ u16 f2bf(float f) {
    return __builtin_bit_cast(u16, (__bf16)f);
}

static __device__ __forceinline__ float bf2f(u16 h) {
    return __uint_as_float((u32)h << 16);
}

static __device__ __forceinline__ short8 ld8(const u16* p) {
    return *(const short8*)p;
}

static __device__ __forceinline__ f32x4 mfma_bf16(short8 a, short8 b, f32x4 c) {
    return __builtin_amdgcn_mfma_f32_16x16x32_bf16(
        __builtin_bit_cast(bf16x8, a), __builtin_bit_cast(bf16x8, b), c, 0, 0, 0);
}

// ---------------- fused prep: x/y transpose -> FRAGMENT-MAJOR + weight cvt + mask^T ----------------
// R17 post-mortem: fragment-major K/V cut attn 52->~38us (L2-transaction fix). proj3's
// A-operand has the same disease (16 lines/load at 1KB row stride). Fix at producer:
// XF/YF[b][t/32][ks:16][half:2][lane:64][8], lane=q*16+col, value x^T[t][i] with
// t=32tt+half*16+col, i=ks*32+q*8+j  ->  every proj3 A ld8 = 64x16B contiguous.
__global__ __launch_bounds__(256) void k_prep(const float* __restrict__ x, const float* __restrict__ y,
                                              const float* __restrict__ wk, const float* __restrict__ wv,
                                              const float* __restrict__ wq, const float* __restrict__ wf,
                                              const float* __restrict__ mask,
                                              u16* __restrict__ xt, u16* __restrict__ yt,
                                              u16* __restrict__ wkb, u16* __restrict__ wvb,
                                              u16* __restrict__ wqb, u16* __restrict__ wfb,
                                              u16* __restrict__ mt, u32* __restrict__ mflag) {
    __shared__ float tile[64][65];
    int bid = blockIdx.x;
    if (bid < 1024) {
        // transpose + cvt + fragment-pack: src[b][i][t] f32 -> XF/YF
        int bx = bid & 31, by = (bid >> 5) & 7, bz = bid >> 8;
        int tsel = bz >> 1, b = bz & 1;
        const float* src = tsel ? y : x;
        u16* dst = tsel ? yt : xt;
        int t0 = bx * 64, i0 = by * 64;
        int tx = threadIdx.x & 15, ty = threadIdx.x >> 4;
#pragma unroll
        for (int r = 0; r < 4; r++) {
            int i = ty + r * 16;
            *(float4*)&tile[i][tx * 4] =
                *(const float4*)(src + (size_t)(b * CI + i0 + i) * T_ + t0 + tx * 4);
        }
        __syncthreads();
        int tx2 = threadIdx.x & 7, ty2 = threadIdx.x >> 3;   // tx2: 8-i chunk, ty2: t row (0..31)
        int ib = i0 + tx2 * 8;
        int ks = ib >> 5, q = (ib >> 3) & 3;
        int col = ty2 & 15, half = (ty2 >> 4) & 1;
#pragma unroll
        for (int r = 0; r < 2; r++) {
            int tl = ty2 + r * 32;                            // local t (0..63)
            int tt = (t0 + tl) >> 5;
            short8 o;
#pragma unroll
            for (int j = 0; j < 8; j++)
                o[j] = (short)f2bf(tile[tx2 * 8 + j][tl]);
            *(short8*)(dst + ((((size_t)b * 64 + tt) * 16 + ks) * 2 + half) * 512
                           + (q * 16 + col) * 8) = o;
        }
    } else if (bid < 1536) {
        // weight cvt, 8 elems/thread
        int off = ((bid - 1024) * 256 + threadIdx.x) * 8;
        int w = off >> 18, r = off & 262143;
        const float* s = (w == 0) ? wk : (w == 1) ? wv : (w == 2) ? wq : wf;
        u16* d = (w == 0) ? wkb : (w == 1) ? wvb : (w == 2) ? wqb : wfb;
        float4 a0 = *(const float4*)(s + r);
        float4 a1 = *(const float4*)(s + r + 4);
        short8 o;
        o[0] = f2bf(a0.x); o[1] = f2bf(a0.y); o[2] = f2bf(a0.z); o[3] = f2bf(a0.w);
        o[4] = f2bf(a1.x); o[5] = f2bf(a1.y); o[6] = f2bf(a1.z); o[7] = f2bf(a1.w);
        *(short8*)(d + r) = o;
    } else {
        // mask transpose + pre-scale; detect any-nonzero
        int mb = bid - 1536;
        int bx = mb & 31, by = mb >> 5;
        int t0 = bx * 64, s0 = by * 64;
        int tx = threadIdx.x & 15, ty = threadIdx.x >> 4;
        const float msc = 0.125f * 1.44269504088896f;
        bool nz = false;
#pragma unroll
        for (int r = 0; r < 4; r++) {
            int t = ty + r * 16;
            float4 v = *(const float4*)(mask + (size_t)(t0 + t) * S_ + s0 + tx * 4);
            nz |= (v.x != 0.0f) | (v.y != 0.0f) | (v.z != 0.0f) | (v.w != 0.0f);
            *(float4*)&tile[t][tx * 4] = v;
        }
        if (mflag && __any(nz) && (threadIdx.x & 63) == 0)
            atomicOr(mflag, 1u);
        __syncthreads();
        int tx2 = threadIdx.x & 7, ty2 = threadIdx.x >> 3;
#pragma unroll
        for (int r = 0; r < 2; r++) {
            int s = ty2 + r * 32;
            short8 o;
#pragma unroll
            for (int j = 0; j < 8; j++)
                o[j] = (short)f2bf(tile[tx2 * 8 + j][s] * msc);
            *(short8*)(mt + (size_t)(s0 + s) * T_ + t0 + tx2 * 8) = o;
        }
    }
}

// ---------------- fused projection GEMMs (64t x 128e, pipelined, fragment-major A) ----------------
// A-loads now from XF/YF: afb + ks*1024 (+512 for the +16t half) = 1KB bursts.
// K/V outputs fragment-major (R17, proven): KF/VF[bh][t/32][piece:4][lane:64][8].
// p = p_base + (blockIdx.x>>8): 0=Q (YF->QT, pre-scaled by sc), 1=K->KF, 2=V->VF.
__global__ __launch_bounds__(256) void k_proj3(const u16* __restrict__ xt, const u16* __restrict__ yt,
                                               const u16* __restrict__ wkb, const u16* __restrict__ wvb,
                                               const u16* __restrict__ wqb,
                                               u16* __restrict__ kfd, u16* __restrict__ vfd,
                                               u16* __restrict__ qtd, int p_base) {
    int bi = blockIdx.x;
    int p = p_base + (bi >> 8);
    int r = bi & 255;
    int et = r & 3, tt = r >> 2;
    int wv = threadIdx.x >> 6, lane = threadIdx.x & 63;
    int col = lane & 15, q = lane >> 4;
    int b = tt >> 5;
    int t0 = (tt & 31) * 64 + (wv >> 1) * 32;
    int e0 = et * 128 + (wv & 1) * 64;
    const u16* src = (p == 0) ? yt : xt;
    const u16* wb  = (p == 0) ? wqb : (p == 1) ? wkb : wvb;
    const u16* afb = src + ((size_t)b * 64 + (t0 >> 5)) * 16384 + lane * 8;
    const u16* bp0 = wb + (size_t)(e0 + col) * CI + q * 8;
    f32x4 acc[2][4] = {};
    short8 a0 = ld8(afb), a1 = ld8(afb + 512);
    short8 b0 = ld8(bp0), b1 = ld8(bp0 + 16 * CI);
    short8 b2 = ld8(bp0 + 32 * CI), b3 = ld8(bp0 + 48 * CI);
#pragma unroll
    for (int ks = 0; ks < 16; ks++) {
        short8 na0, na1, nb0, nb1, nb2, nb3;
        if (ks < 15) {
            na0 = ld8(afb + (ks + 1) * 1024);
            na1 = ld8(afb + (ks + 1) * 1024 + 512);
            nb0 = ld8(bp0 + (ks + 1) * 32);
            nb1 = ld8(bp0 + 16 * CI + (ks + 1) * 32);
            nb2 = ld8(bp0 + 32 * CI + (ks + 1) * 32);
            nb3 = ld8(bp0 + 48 * CI + (ks + 1) * 32);
        }
        acc[0][0] = mfma_bf16(a0, b0, acc[0][0]); acc[1][0] = mfma_bf16(a1, b0, acc[1][0]);
        acc[0][1] = mfma_bf16(a0, b1, acc[0][1]); acc[1][1] = mfma_bf16(a1, b1, acc[1][1]);
        acc[0][2] = mfma_bf16(a0, b2, acc[0][2]); acc[1][2] = mfma_bf16(a1, b2, acc[1][2]);
        acc[0][3] = mfma_bf16(a0, b3, acc[0][3]); acc[1][3] = mfma_bf16(a1, b3, acc[1][3]);
        if (ks < 15) {
            a0 = na0; a1 = na1; b0 = nb0; b1 = nb1; b2 = nb2; b3 = nb3;
        }
    }
    const float qs = 0.180336880f;   // 0.125 * log2(e), folded into Q
    if (p == 0) {
#pragma unroll
        for (int mt = 0; mt < 2; mt++)
#pragma unroll
            for (int nt = 0; nt < 4; nt++) {
                int e = e0 + nt * 16 + col, h = e >> 6, k = e & 63;
                u16* dp = qtd + ((size_t)(b * 8 + h) * T_ + t0 + mt * 16 + q * 4) * DK + k;
                dp[0] = f2bf(acc[mt][nt][0] * qs);
                dp[DK] = f2bf(acc[mt][nt][1] * qs);
                dp[2 * DK] = f2bf(acc[mt][nt][2] * qs);
                dp[3 * DK] = f2bf(acc[mt][nt][3] * qs);
            }
    } else if (p == 1) {
        // K -> fragment-major KF. Value acc[mt][nt][r]: t = t0+mt*16+q*4+r, k = e&63.
        int ttk = t0 >> 5;
#pragma unroll
        for (int mt = 0; mt < 2; mt++) {
            int cb = (mt * 2 + (q >> 1)) << 2;
#pragma unroll
            for (int nt = 0; nt < 4; nt++) {
                int e = e0 + nt * 16 + col, h = e >> 6, k = e & 63;
                int pp = ((q & 1) << 1) | (k >> 5);
                int lf = (((k & 31) >> 3) << 4) + cb;
                u16* dp = kfd + ((((size_t)(b * 8 + h) * 64 + ttk) * 4 + pp) * 64 + lf) * 8 + (k & 7);
                dp[0]  = f2bf(acc[mt][nt][0]);
                dp[8]  = f2bf(acc[mt][nt][1]);
                dp[16] = f2bf(acc[mt][nt][2]);
                dp[24] = f2bf(acc[mt][nt][3]);
            }
        }
    } else {
        // V -> fragment-major VF. Value acc[mt][nt][r]: t = t0+mt*16+q*4+r, v = e&63.
        int ttv = t0 >> 5;
        int j0 = (q & 1) * 4;
#pragma unroll
        for (int mt = 0; mt < 2; mt++) {
            int lf = col | ((mt * 2 + (q >> 1)) << 4);
#pragma unroll
            for (int nt = 0; nt < 4; nt++) {
                int e = e0 + nt * 16 + col, h = e >> 6;
                uint2 pk;
                pk.x = f2bf(acc[mt][nt][0]) | ((u32)f2bf(acc[mt][nt][1]) << 16);
                pk.y = f2bf(acc[mt][nt][2]) | ((u32)f2bf(acc[mt][nt][3]) << 16);
                *(uint2*)(vfd + ((((size_t)(b * 8 + h) * 64 + ttv) * 4 + nt) * 64 + lf) * 8 + j0) = pk;
            }
        }
    }
}

// ---------------- flash attention: fragment-coalesced K/V, runtime mask-skip ----------------

// masked iteration (mv pre-scaled, Q pre-scaled -> add)
#define ATTN_ITER_M(TT, KC, MC4, MCF, KN, MN4, MNF, TTN)  do {                      \
    short8 vb0 = ld8(vfb + ((TT) * 4 + 0) * 512);                                   \
    short8 vb1 = ld8(vfb + ((TT) * 4 + 1) * 512);                                   \
    short8 vb2 = ld8(vfb + ((TT) * 4 + 2) * 512);                                   \
    short8 vb3 = ld8(vfb + ((TT) * 4 + 3) * 512);                                   \
    f32x4 s0g[4], s1g[4];                                                           \
    __builtin_amdgcn_s_setprio(1);                                                  \
    _Pragma("unroll") for (int g = 0; g < 4; g++) {                                 \
        f32x4 z = {};                                                               \
        s0g[g] = mfma_bf16(KC[0], qa[g][0], z);                                     \
        s0g[g] = mfma_bf16(KC[1], qa[g][1], s0g[g]);                                \
        s1g[g] = mfma_bf16(KC[2], qa[g][0], z);                                     \
        s1g[g] = mfma_bf16(KC[3], qa[g][1], s1g[g]);                                \
    }                                                                               \
    __builtin_amdgcn_s_setprio(0);                                                  \
    KN[0] = ld8(kfb + ((TTN) * 4 + 0) * 512);                                       \
    KN[1] = ld8(kfb + ((TTN) * 4 + 1) * 512);                                       \
    KN[2] = ld8(kfb + ((TTN) * 4 + 2) * 512);                                       \
    KN[3] = ld8(kfb + ((TTN) * 4 + 3) * 512);                                       \
    if constexpr (MODE == 1) {                                                      \
        _Pragma("unroll") for (int g = 0; g < 4; g++) {                             \
            MN4[g][0] = *(const ushort4*)(mtb[g] + (TTN) * 32);                     \
            MN4[g][1] = *(const ushort4*)(mtb[g] + (TTN) * 32 + 4);                 \
        }                                                                           \
    } else {                                                                        \
        _Pragma("unroll") for (int g = 0; g < 4; g++)                               \
        _Pragma("unroll") for (int st = 0; st < 2; st++)                            \
        _Pragma("unroll") for (int rr = 0; rr < 4; rr++)                            \
            MNF[g][st * 4 + rr] =                                                   \
                mbs[g][(size_t)((TTN) * 32 + q * 8 + st * 4 + rr) * S_] * msc;      \
    }                                                                               \
    _Pragma("unroll") for (int g = 0; g < 4; g++) {                                 \
        bf16x8 pbv;                                                                 \
        float lsum = 0.f;                                                           \
        _Pragma("unroll") for (int i = 0; i < 8; i++) {                             \
            float sv = (i < 4) ? s0g[g][i & 3] : s1g[g][i & 3];                     \
            float mv;                                                               \
            if constexpr (MODE == 1)                                                \
                mv = bf2f(((const u16*)&MC4[g][i >> 2])[i & 3]);                    \
            else                                                                    \
                mv = MCF[g][i];                                                     \
            float p = __builtin_amdgcn_exp2f(sv + mv);                              \
            lsum += p;                                                              \
            pbv[i] = (__bf16)p;                                                     \
        }                                                                           \
        l_part[g] += lsum;                                                          \
        short8 pa = __builtin_bit_cast(short8, pbv);                                \
        __builtin_amdgcn_s_setprio(1);                                              \
        oacc[g][0] = mfma_bf16(vb0, pa, oacc[g][0]);                                \
        oacc[g][1] = mfma_bf16(vb1, pa, oacc[g][1]);                                \
        oacc[g][2] = mfma_bf16(vb2, pa, oacc[g][2]);                                \
        oacc[g][3] = mfma_bf16(vb3, pa, oacc[g][3]);                                \
        __builtin_amdgcn_s_setprio(0);                                              \
    }                                                                               \
} while (0)

// maskless iteration: V top-loaded, K ping-pong, no mask loads
#define ATTN_ITER_NM(TT, KC, KN, TTN)  do {                                         \
    short8 vb0 = ld8(vfb + ((TT) * 4 + 0) * 512);                                   \
    short8 vb1 = ld8(vfb + ((TT) * 4 + 1) * 512);                                   \
    short8 vb2 = ld8(vfb + ((TT) * 4 + 2) * 512);                                   \
    short8 vb3 = ld8(vfb + ((TT) * 4 + 3) * 512);                                   \
    f32x4 s0g[4], s1g[4];                                                           \
    __builtin_amdgcn_s_setprio(1);                                                  \
    _Pragma("unroll") for (int g = 0; g < 4; g++) {                                 \
        f32x4 z = {};                                                               \
        s0g[g] = mfma_bf16(KC[0], qa[g][0], z);                                     \
        s0g[g] = mfma_bf16(KC[1], qa[g][1], s0g[g]);                                \
        s1g[g] = mfma_bf16(KC[2], qa[g][0], z);                                     \
        s1g[g] = mfma_bf16(KC[3], qa[g][1], s1g[g]);                                \
    }                                                                               \
    __builtin_amdgcn_s_setprio(0);                                                  \
    KN[0] = ld8(kfb + ((TTN) * 4 + 0) * 512);                                       \
    KN[1] = ld8(kfb + ((TTN) * 4 + 1) * 512);                                       \
    KN[2] = ld8(kfb + ((TTN) * 4 + 2) * 512);                                       \
    KN[3] = ld8(kfb + ((TTN) * 4 + 3) * 512);                                       \
    _Pragma("unroll") for (int g = 0; g < 4; g++) {                                 \
        bf16x8 pbv;                                                                 \
        float lsum = 0.f;                                                           \
        _Pragma("unroll") for (int i = 0; i < 8; i++) {                             \
            float sv = (i < 4) ? s0g[g][i & 3] : s1g[g][i & 3];                     \
            float p = __builtin_amdgcn_exp2f(sv);                                   \
            lsum += p;                                                              \
            pbv[i] = (__bf16)p;                                                     \
        }                                                                           \
        l_part[g] += lsum;                                                          \
        short8 pa = __builtin_bit_cast(short8, pbv);                                \
        __builtin_amdgcn_s_setprio(1);                                              \
        oacc[g][0] = mfma_bf16(vb0, pa, oacc[g][0]);                                \
        oacc[g][1] = mfma_bf16(vb1, pa, oacc[g][1]);                                \
        oacc[g][2] = mfma_bf16(vb2, pa, oacc[g][2]);                                \
        oacc[g][3] = mfma_bf16(vb3, pa, oacc[g][3]);                                \
        __builtin_amdgcn_s_setprio(0);                                              \
    }                                                                               \
} while (0)

template<int MODE>
__global__ __launch_bounds__(512, 2) void k_attn(const u16* __restrict__ kf, const u16* __restrict__ qt,
                                                 const u16* __restrict__ vf, const float* __restrict__ mask,
                                                 const u16* __restrict__ mt, const u32* __restrict__ mflag,
                                                 u16* __restrict__ oa) {
    __shared__ struct { float O[8][16][68]; float L[8][16]; } Sm;   // merge only
    int wv = threadIdx.x >> 6, lane = threadIdx.x & 63;
    int col = lane & 15, q = lane >> 4;
    int bid = blockIdx.x;
    int j = bid >> 3;
    int bh = (bid & 7) * 2 + (j >> 5);
    int s_base = (j & 31) * 64;
    int sg = s_base + col;
    const int tt_begin = wv * 8;          // 8 x 32-t tiles per wave (T/8 = 256)
    const int tt_end = tt_begin + 8;
    short8 qa[4][2];
#pragma unroll
    for (int g = 0; g < 4; g++) {
        const u16* qp = qt + (size_t)(bh * S_ + sg + g * 16) * DK + q * 8;
        qa[g][0] = ld8(qp);
        qa[g][1] = ld8(qp + 32);
    }
    const u16* kfb = kf + (size_t)bh * 131072 + lane * 8;
    const u16* vfb = vf + (size_t)bh * 131072 + lane * 8;
    float l_part[4] = {0.f, 0.f, 0.f, 0.f};
    f32x4 oacc[4][4] = {};
    const float msc = 0.180336880f;   // for the f32-mask fallback

    int use_mask = mflag ? (int)*mflag : 1;

    if (use_mask == 0) {
        short8 kA[4], kB[4];
        kA[0] = ld8(kfb + (tt_begin * 4 + 0) * 512);
        kA[1] = ld8(kfb + (tt_begin * 4 + 1) * 512);
        kA[2] = ld8(kfb + (tt_begin * 4 + 2) * 512);
        kA[3] = ld8(kfb + (tt_begin * 4 + 3) * 512);
        for (int tt = tt_begin; tt < tt_end; tt += 2) {
            ATTN_ITER_NM(tt, kA, kB, tt + 1);
            int ttn2 = (tt + 2 < tt_end) ? (tt + 2) : tt_begin;
            ATTN_ITER_NM(tt + 1, kB, kA, ttn2);
        }
    } else {
        const float* mbs[4];
        const u16* mtb[4];
#pragma unroll
        for (int g = 0; g < 4; g++) {
            mbs[g] = mask + sg + g * 16;
            mtb[g] = mt + (size_t)(sg + g * 16) * T_ + q * 8;
        }
        short8 kA[4], kB[4];
        ushort4 mA4[4][2], mB4[4][2];
        float mAf[4][8], mBf[4][8];
        kA[0] = ld8(kfb + (tt_begin * 4 + 0) * 512);
        kA[1] = ld8(kfb + (tt_begin * 4 + 1) * 512);
        kA[2] = ld8(kfb + (tt_begin * 4 + 2) * 512);
        kA[3] = ld8(kfb + (tt_begin * 4 + 3) * 512);
        if constexpr (MODE == 1) {
#pragma unroll
            for (int g = 0; g < 4; g++) {
                mA4[g][0] = *(const ushort4*)(mtb[g] + tt_begin * 32);
                mA4[g][1] = *(const ushort4*)(mtb[g] + tt_begin * 32 + 4);
            }
        } else {
#pragma unroll
            for (int g = 0; g < 4; g++)
#pragma unroll
                for (int st = 0; st < 2; st++)
#pragma unroll
                    for (int rr = 0; rr < 4; rr++)
                        mAf[g][st * 4 + rr] =
                            mbs[g][(size_t)(tt_begin * 32 + q * 8 + st * 4 + rr) * S_] * msc;
        }
        for (int tt = tt_begin; tt < tt_end; tt += 2) {
            ATTN_ITER_M(tt, kA, mA4, mAf, kB, mB4, mBf, tt + 1);
            int ttn2 = (tt + 2 < tt_end) ? (tt + 2) : tt_begin;
            ATTN_ITER_M(tt + 1, kB, mB4, mBf, kA, mA4, mAf, ttn2);
        }
    }

    // l: reduce per-lane partials over q
#pragma unroll
    for (int g = 0; g < 4; g++) {
        float lr = l_part[g];
        lr += __shfl_xor(lr, 16);
        lr += __shfl_xor(lr, 32);
        l_part[g] = lr;
    }

    // ---- merge of the 8 per-wave T-partials: O = Sum(O_c) / Sum(l_c) ----
    int b = bh >> 3, h = bh & 7;
    __syncthreads();
#pragma unroll
    for (int g = 0; g < 4; g++) {
#pragma unroll
        for (int nt = 0; nt < 4; nt++)
            *(f32x4*)&Sm.O[wv][col][nt * 16 + q * 4] = oacc[g][nt];
        if (lane < 16)
            Sm.L[wv][lane] = l_part[g];
        __syncthreads();
#pragma unroll
        for (int e = 0; e < 2; e++) {
            int f = (int)threadIdx.x + e * 512;
            int s = f >> 6, v = f & 63;
            float acc = 0.f, lt = 0.f;
#pragma unroll
            for (int c = 0; c < 8; c++) {
                acc += Sm.O[c][s][v];
                lt += Sm.L[c][s];
            }
            oa[(size_t)(b * S_ + s_base + g * 16 + s) * E_ + h * DK + v] = f2bf(acc / lt);
        }
        __syncthreads();
    }
}

// ---------------- final GEMM (64s x 64o, grid 512, pipelined) ----------------
__global__ __launch_bounds__(256) void k_final(const u16* __restrict__ oa, const u16* __restrict__ wfb,
                                               const float* __restrict__ bias, float* __restrict__ out) {
    int bi = blockIdx.x;
    int et = bi & 7, tt = bi >> 3;
    int wv = threadIdx.x >> 6, lane = threadIdx.x & 63;
    int col = lane & 15, q = lane >> 4;
    int b = tt >> 5;
    int s0 = (tt & 31) * 64 + (wv >> 1) * 32;
    int o0 = et * 64 + (wv & 1) * 32;
    const u16* ap0 = oa + (size_t)(b * S_ + s0 + col) * E_ + q * 8;
    const u16* bp0 = wfb + (size_t)(o0 + col) * E_ + q * 8;
    f32x4 acc[2][2] = {};
    short8 a0 = ld8(ap0), a1 = ld8(ap0 + 16 * E_);
    short8 b0 = ld8(bp0), b1 = ld8(bp0 + 16 * E_);
#pragma unroll
    for (int ks = 0; ks < 16; ks++) {
        short8 na0, na1, nb0, nb1;
        if (ks < 15) {
            na0 = ld8(ap0 + (ks + 1) * 32);
            na1 = ld8(ap0 + 16 * E_ + (ks + 1) * 32);
            nb0 = ld8(bp0 + (ks + 1) * 32);
            nb1 = ld8(bp0 + 16 * E_ + (ks + 1) * 32);
        }
        acc[0][0] = mfma_bf16(a0, b0, acc[0][0]); acc[1][0] = mfma_bf16(a1, b0, acc[1][0]);
        acc[0][1] = mfma_bf16(a0, b1, acc[0][1]); acc[1][1] = mfma_bf16(a1, b1, acc[1][1]);
        if (ks < 15) {
            a0 = na0; a1 = na1; b0 = nb0; b1 = nb1;
        }
    }
#pragma unroll
    for (int mt = 0; mt < 2; mt++)
#pragma unroll
        for (int nt = 0; nt < 2; nt++) {
            int o = o0 + nt * 16 + col;
            float bn = bias[o];
#pragma unroll
            for (int r = 0; r < 4; r++) {
                int s = s0 + mt * 16 + q * 4 + r;
                out[(size_t)(b * S_ + s) * CO + o] = acc[mt][nt][r] + bn;
            }
        }
}

extern "C" void kernel_launch(void* const* d_in, const int* in_sizes, int n_in,
                              void* d_out, int out_size, void* d_ws, size_t ws_size,
                              hipStream_t stream) {
    const float* x    = (const float*)d_in[0];
    const float* y    = (const float*)d_in[1];
    const float* mask = (const float*)d_in[2];
    const float* Wk   = (const float*)d_in[3];
    const float* Wv   = (const float*)d_in[4];
    const float* Wq   = (const float*)d_in[5];
    const float* Wf   = (const float*)d_in[6];
    const float* bias = (const float*)d_in[7];
    float* out = (float*)d_out;

    u16* ws = (u16*)d_ws;
    u16* XT  = ws;                 // x fragment-major; reused as OA after projections
    u16* YT  = XT + 2097152;       // y fragment-major; fallback VF alias
    u16* WKB = YT + 2097152;
    u16* WVB = WKB + 262144;
    u16* WQB = WVB + 262144;
    u16* WFB = WQB + 262144;
    u16* KF  = WFB + 262144;       // fragment-major K, 4 MiB
    u16* QT  = KF + 2097152;       // end = 18 MiB
    u16* MT  = QT + 2097152;       // mask^T bf16 pre-scaled, end = 26 MiB
    u16* VFs = MT + 4194304;       // fragment-major V, end = 30 MiB
    u32* MF  = (u32*)(VFs + 2097152);
    u16* OA  = XT;

    int use_mt   = (ws_size >= (size_t)27262976) ? 1 : 0;
    int has_vt   = (ws_size >= (size_t)31457280) ? 1 : 0;
    int has_flag = (ws_size >= (size_t)31457344) ? 1 : 0;
    u16* VF = has_vt ? VFs : YT;
    u32* MFp = (use_mt && has_flag) ? MF : (u32*)nullptr;

    if (MFp)
        (void)hipMemsetAsync(MFp, 0, 4, stream);
    k_prep<<<use_mt ? 2560 : 1536, 256, 0, stream>>>(x, y, Wk, Wv, Wq, Wf, mask,
                                                     XT, YT, WKB, WVB, WQB, WFB, MT, MFp);
    if (has_vt) {
        k_proj3<<<768, 256, 0, stream>>>(XT, YT, WKB, WVB, WQB, KF, VF, QT, 0);
    } else {
        k_proj3<<<512, 256, 0, stream>>>(XT, YT, WKB, WVB, WQB, KF, VF, QT, 0);
        k_proj3<<<256, 256, 0, stream>>>(XT, YT, WKB, WVB, WQB, KF, VF, QT, 2);
    }
    if (use_mt)
        k_attn<1><<<512, 512, 0, stream>>>(KF, QT, VF, mask, MT, MFp, OA);
    else
        k_attn<0><<<512, 512, 0, stream>>>(KF, QT, VF, mask, MT, MFp, OA);
    k_final<<<512, 256, 0, stream>>>(OA, WFB, bias, out);
}